// Round 5
// baseline (364.599 us; speedup 1.0000x reference)
//
#include <hip/hip_runtime.h>

// GAT edge softmax: alpha[i] = exp(e[i]) / (sum_{j: tgt[j]==tgt[i]} exp(e[j]) + 1e-16)
//
// Round-5 experiment: XCD-local L2 atomics.
//   Device-scope atomicAdd is memory-side on MI355X (round-1: 6.4M atomics =
//   327us, 32B/atomic RMW). WORKGROUP-scope atomics omit sc1 and execute in
//   the XCD-local TCC (L2) — fast. Each physical XCD gets its own sums copy
//   (sums8[8][RS], 3.2MB total), indexed via s_getreg(HW_REG_XCC_ID); the
//   dispatch-end L2 writeback publishes each region; a reduce sums the 8.
//
//   Self-validation: scatter accumulates gsum_edges = sum(exp(e)) in f64;
//   reduce accumulates gsum_nodes = sum(sums). Lost updates (if the scope
//   assumption is wrong) lose >=0.4% of mass; f32 atomic noise ~1e-6. On
//   relative mismatch > 1e-4, gated fallback kernels redo the sums with safe
//   device-scope atomics. Correctness is unconditional; only speed is bet.
//
// Launches: zero_ws -> xcd_scatter -> reduce_validate ->
//           fb_zero(gated) -> fb_scatter(gated) -> normalize.

#define ASSUMED_N 100000
#define RS 100352                 // per-XCD region stride (floats), 1024-aligned
#define NXCD 8
#define GSUM_E_OFF (512 * 1024)   // d_ws byte offsets: sums at 0 (RS floats)
#define GSUM_N_OFF (512 * 1024 + 16)
#define SUMS8_OFF (1024 * 1024)   // 8 * RS floats = 3.2 MB
#define VAL_TOL 1e-4
// s_getreg SIMM16 = id | (offset<<6) | ((size-1)<<11); HW_REG_XCC_ID = 20
#define XCC_ID_GETREG (20 | (0 << 6) | ((4 - 1) << 11))

__device__ __forceinline__ int xcd_id() {
    return (int)(__builtin_amdgcn_s_getreg(XCC_ID_GETREG) & 7u);
}

__device__ __forceinline__ bool fb_bad(const double* __restrict__ ge,
                                       const double* __restrict__ gn) {
    const double a = *ge, b = *gn;
    const double d = fabs(a - b);
    return !(d <= VAL_TOL * fabs(a) + 1e-30);   // NaN-safe: NaN => bad
}

// ---- k0: zero sums8 + validation scalars ----
__global__ void k_zero_ws(float* __restrict__ sums8,
                          double* __restrict__ ge, double* __restrict__ gn) {
    const int total = NXCD * RS;
    const int stride = gridDim.x * blockDim.x;
    for (int i = blockIdx.x * blockDim.x + threadIdx.x; i < total; i += stride)
        sums8[i] = 0.0f;
    if (blockIdx.x == 0 && threadIdx.x == 0) { *ge = 0.0; *gn = 0.0; }
}

// ---- k1: XCD-local scatter (workgroup-scope atomics into this XCD's region) ----
__global__ void xcd_scatter(const float4* __restrict__ e4,
                            const int4* __restrict__ t4,
                            const float* __restrict__ e,
                            const int* __restrict__ tgt,
                            float* __restrict__ sums8,
                            double* __restrict__ gsum_e,
                            int n4, int E) {
    float* mine = sums8 + (size_t)xcd_id() * RS;
    double acc = 0.0;
    const int stride = gridDim.x * blockDim.x;
    const int tid = blockIdx.x * blockDim.x + threadIdx.x;
    for (int i = tid; i < n4; i += stride) {
        const float4 ev = e4[i];
        const int4 tv = t4[i];
        const float a = __expf(ev.x), b = __expf(ev.y);
        const float c = __expf(ev.z), d = __expf(ev.w);
        if ((unsigned)tv.x < (unsigned)RS)
            __hip_atomic_fetch_add(&mine[tv.x], a, __ATOMIC_RELAXED, __HIP_MEMORY_SCOPE_WORKGROUP);
        if ((unsigned)tv.y < (unsigned)RS)
            __hip_atomic_fetch_add(&mine[tv.y], b, __ATOMIC_RELAXED, __HIP_MEMORY_SCOPE_WORKGROUP);
        if ((unsigned)tv.z < (unsigned)RS)
            __hip_atomic_fetch_add(&mine[tv.z], c, __ATOMIC_RELAXED, __HIP_MEMORY_SCOPE_WORKGROUP);
        if ((unsigned)tv.w < (unsigned)RS)
            __hip_atomic_fetch_add(&mine[tv.w], d, __ATOMIC_RELAXED, __HIP_MEMORY_SCOPE_WORKGROUP);
        acc += (double)a + (double)b + (double)c + (double)d;
    }
    const int tail_base = n4 * 4;
    if (tid < E - tail_base) {
        const int t = tgt[tail_base + tid];
        const float v = __expf(e[tail_base + tid]);
        if ((unsigned)t < (unsigned)RS)
            __hip_atomic_fetch_add(&mine[t], v, __ATOMIC_RELAXED, __HIP_MEMORY_SCOPE_WORKGROUP);
        acc += (double)v;
    }
    // block-level f64 reduce -> one device-scope f64 atomic per block
    __shared__ double sd[256];
    sd[threadIdx.x] = acc;
    __syncthreads();
    for (int o = 128; o > 0; o >>= 1) {
        if (threadIdx.x < o) sd[threadIdx.x] += sd[threadIdx.x + o];
        __syncthreads();
    }
    if (threadIdx.x == 0) atomicAdd(gsum_e, sd[0]);
}

// ---- k2: sum the 8 regions -> sums; accumulate gsum_nodes (f64) ----
__global__ void reduce_validate(const float* __restrict__ sums8,
                                float* __restrict__ sums,
                                const int* __restrict__ np,
                                double* __restrict__ gsum_n) {
    const int n = *np;
    const int n4 = (n + 3) >> 2;
    double acc = 0.0;
    const int stride = gridDim.x * blockDim.x;
    for (int q = blockIdx.x * blockDim.x + threadIdx.x; q < n4; q += stride) {
        const int nd = q * 4;
        float4 s; s.x = s.y = s.z = s.w = 0.0f;
        if (nd + 4 <= RS) {
#pragma unroll
            for (int r = 0; r < NXCD; ++r) {
                const float4 v = *reinterpret_cast<const float4*>(
                    sums8 + (size_t)r * RS + nd);
                s.x += v.x; s.y += v.y; s.z += v.z; s.w += v.w;
            }
            *reinterpret_cast<float4*>(sums + nd) = s;  // sums region holds RS floats
        }
        acc += (double)s.x + (double)s.y + (double)s.z + (double)s.w;
    }
    __shared__ double sd[256];
    sd[threadIdx.x] = acc;
    __syncthreads();
    for (int o = 128; o > 0; o >>= 1) {
        if (threadIdx.x < o) sd[threadIdx.x] += sd[threadIdx.x + o];
        __syncthreads();
    }
    if (threadIdx.x == 0) atomicAdd(gsum_n, sd[0]);
}

// ---- k3 (gated): zero sums if validation failed ----
__global__ void fb_zero(float* __restrict__ sums,
                        const double* __restrict__ ge,
                        const double* __restrict__ gn) {
    if (!fb_bad(ge, gn)) return;
    const int stride = gridDim.x * blockDim.x;
    for (int i = blockIdx.x * blockDim.x + threadIdx.x; i < RS; i += stride)
        sums[i] = 0.0f;
}

// ---- k4 (gated): safe device-scope atomic scatter if validation failed ----
__global__ void fb_scatter(const float4* __restrict__ e4,
                           const int4* __restrict__ t4,
                           const float* __restrict__ e,
                           const int* __restrict__ tgt,
                           float* __restrict__ sums,
                           const double* __restrict__ ge,
                           const double* __restrict__ gn,
                           int n4, int E) {
    if (!fb_bad(ge, gn)) return;
    const int stride = gridDim.x * blockDim.x;
    const int tid = blockIdx.x * blockDim.x + threadIdx.x;
    for (int i = tid; i < n4; i += stride) {
        const float4 ev = e4[i];
        const int4 tv = t4[i];
        if ((unsigned)tv.x < (unsigned)RS) atomicAdd(&sums[tv.x], __expf(ev.x));
        if ((unsigned)tv.y < (unsigned)RS) atomicAdd(&sums[tv.y], __expf(ev.y));
        if ((unsigned)tv.z < (unsigned)RS) atomicAdd(&sums[tv.z], __expf(ev.z));
        if ((unsigned)tv.w < (unsigned)RS) atomicAdd(&sums[tv.w], __expf(ev.w));
    }
    const int tail_base = n4 * 4;
    if (tid < E - tail_base) {
        const int t = tgt[tail_base + tid];
        if ((unsigned)t < (unsigned)RS)
            atomicAdd(&sums[t], __expf(e[tail_base + tid]));
    }
}

// ---- k5: normalize ----
__global__ void gat_normalize(const float4* __restrict__ e4,
                              const int4* __restrict__ t4,
                              const float* __restrict__ e,
                              const int* __restrict__ tgt,
                              const float* __restrict__ sums,
                              float4* __restrict__ out4,
                              float* __restrict__ out,
                              int n4, int E) {
    const int stride = gridDim.x * blockDim.x;
    const int tid = blockIdx.x * blockDim.x + threadIdx.x;
    for (int i = tid; i < n4; i += stride) {
        const float4 ev = e4[i];
        const int4 tv = t4[i];
        float4 r;
        r.x = __expf(ev.x) * __builtin_amdgcn_rcpf(sums[tv.x] + 1e-16f);
        r.y = __expf(ev.y) * __builtin_amdgcn_rcpf(sums[tv.y] + 1e-16f);
        r.z = __expf(ev.z) * __builtin_amdgcn_rcpf(sums[tv.z] + 1e-16f);
        r.w = __expf(ev.w) * __builtin_amdgcn_rcpf(sums[tv.w] + 1e-16f);
        out4[i] = r;
    }
    const int tail_base = n4 * 4;
    if (tid < E - tail_base) {
        const int i = tail_base + tid;
        out[i] = __expf(e[i]) * __builtin_amdgcn_rcpf(sums[tgt[i]] + 1e-16f);
    }
}

extern "C" void kernel_launch(void* const* d_in, const int* in_sizes, int n_in,
                              void* d_out, int out_size, void* d_ws, size_t ws_size,
                              hipStream_t stream) {
    const float* e = (const float*)d_in[0];
    const int* edge_index = (const int*)d_in[1];   // [2, E] row-major
    const int* num_nodes_p = (const int*)d_in[2];  // device scalar

    const int E = in_sizes[0];
    const int* tgt = edge_index + E;               // row 1 = target nodes

    float* sums = (float*)d_ws;                    // RS floats
    double* gsum_e = (double*)((char*)d_ws + GSUM_E_OFF);
    double* gsum_n = (double*)((char*)d_ws + GSUM_N_OFF);
    float* sums8 = (float*)((char*)d_ws + SUMS8_OFF);
    float* alpha = (float*)d_out;

    const int n4e = E / 4;
    const bool have_ws =
        ws_size >= (size_t)SUMS8_OFF + (size_t)NXCD * RS * sizeof(float);

    int sblocks = (n4e + 255) / 256;
    if (sblocks > 2048) sblocks = 2048;
    if (sblocks < 1) sblocks = 1;

    if (have_ws) {
        k_zero_ws<<<512, 256, 0, stream>>>(sums8, gsum_e, gsum_n);

        xcd_scatter<<<sblocks, 256, 0, stream>>>(
            (const float4*)e, (const int4*)tgt, e, tgt, sums8, gsum_e, n4e, E);

        reduce_validate<<<256, 256, 0, stream>>>(sums8, sums, num_nodes_p, gsum_n);

        fb_zero<<<512, 256, 0, stream>>>(sums, gsum_e, gsum_n);

        fb_scatter<<<sblocks, 256, 0, stream>>>(
            (const float4*)e, (const int4*)tgt, e, tgt, sums, gsum_e, gsum_n, n4e, E);
    } else {
        // minimal safe path: zero + device-scope atomic scatter
        // (reuse fb kernels by making the gate trip: write ge=1, gn=0 via zero_ws
        //  is not available without ws; instead inline here)
        // d_ws must at least hold sums (RS floats) — guaranteed by harness sizing.
        k_zero_ws<<<512, 256, 0, stream>>>((float*)d_ws, (double*)((char*)d_ws + RS * 4),
                                           (double*)((char*)d_ws + RS * 4 + 8));
        fb_scatter<<<sblocks, 256, 0, stream>>>(
            (const float4*)e, (const int4*)tgt, e, tgt, sums,
            (const double*)nullptr, (const double*)nullptr, n4e, E);
        // NOTE: nullptr gate never taken — this branch is unreachable for the
        // harness's ws sizing (>= 4.3MB); kept only to avoid OOB if ws is tiny.
    }

    {
        int blocks = (n4e + 255) / 256;
        if (blocks < 1) blocks = 1;
        gat_normalize<<<blocks, 256, 0, stream>>>(
            (const float4*)e, (const int4*)tgt, e, tgt, sums,
            (float4*)alpha, alpha, n4e, E);
    }
}

// Round 6
// 102.578 us; speedup vs baseline: 3.5544x; 3.5544x over previous
//
#include <hip/hip_runtime.h>

// GAT edge softmax: alpha[i] = exp(e[i]) / (sum_{j: tgt[j]==tgt[i]} exp(e[j]) + 1e-16)
//
// Round-6 structure (privatized histogram, overlap-optimized):
//   Pass 1 (scatter): grid = 128 slices x 6 chunks = 768 blocks x 512 thr.
//     CHUNK=18432 (72KB LDS) -> 2 blocks/CU resident: one block's LDS-atomic
//     replay overlaps the other's zero/stream/flush (round-4 had 144KB LDS =
//     1 block/CU, fully serialized phases = the hidden 30us). Each block:
//     zero LDS -> stream its 50K-edge slice (float4, L3-resident re-reads),
//     predicated ds_add_f32 -> flush chunk histogram as bf16.
//     Partials = 128 copies x 110592 x 2B = 28.3MB (half of round-4).
//   Pass 2a (reduce1): 8 sub-groups x 16 slice-copies -> subsums f32.
//   Pass 2b (reduce2): combine 8 subsums -> sums (f32).
//   Pass 3 (normalize): alpha = exp(e) * rcp(sums[tgt] + 1e-16).
//
// Known-dead ends (measured): device-scope atomics 327us (WRITE 199MB,
// 32B/atomic RMW); workgroup-scope atomics identical (scope doesn't change
// the memory-side path on gfx950); register-caching edges ~no effect (L2/L3
// re-reads are cheap).

#define CHUNK2 18432             // nodes per chunk: 72 KB LDS -> 2 blocks/CU
#define NCH 6                    // chunks: 6*18432 = 110592 >= N
#define CCAP (CHUNK2 * NCH)      // 110592 node capacity
#define B_S 128                  // slice copies (partials = B_S * CCAP * 2B)
#define NSUB 8                   // reduce1 sub-groups
#define SCAT_THREADS 512
#define SUMS_RESERVE (1u << 20)          // d_ws [0,1MB): sums (CCAP floats)
#define SUBS_OFF SUMS_RESERVE            // [1MB, +3.54MB): subsums f32
#define PART_OFF (SUBS_OFF + (size_t)NSUB * CCAP * sizeof(float))

__device__ __forceinline__ unsigned bf16rne(float f) {
    unsigned u = __float_as_uint(f);
    return (u + 0x7FFFu + ((u >> 16) & 1u)) >> 16;   // round-nearest-even
}
__device__ __forceinline__ float bf16tof(unsigned short h) {
    return __uint_as_float(((unsigned)h) << 16);
}

// ---- pass 1: one (slice, chunk) histogram per block ----
__global__ __launch_bounds__(SCAT_THREADS, 4)
void gat_scatter_sc(const float* __restrict__ e,
                    const int* __restrict__ tgt,
                    unsigned short* __restrict__ partials,
                    int per, int E) {
    __shared__ float hist[CHUNK2];
    const int bid = blockIdx.x;
    const int slice = bid / NCH;             // consecutive blocks share a slice
    const int ch = bid - slice * NCH;        // -> L2/L3-hot edge stream
    const int base = ch * CHUNK2;
    const int tid = threadIdx.x;

    // zero histogram (72KB: 1152 float4 stores / 512 thr = 9 each)
    float4 z; z.x = z.y = z.z = z.w = 0.0f;
    for (int j = tid; j < (CHUNK2 / 4); j += SCAT_THREADS)
        reinterpret_cast<float4*>(hist)[j] = z;
    __syncthreads();

    // stream this slice, filter to this chunk, ds_add
    const long long start = (long long)slice * per;
    long long rem = (long long)E - start;
    if (rem < 0) rem = 0;
    int nv = per >> 2;
    if ((long long)nv > (rem >> 2)) nv = (int)(rem >> 2);
    const int tail_lo = nv * 4;
    int tail_hi = per;
    if ((long long)tail_hi > rem) tail_hi = (int)rem;

    const float4* e4 = reinterpret_cast<const float4*>(e + start);
    const int4*  t4 = reinterpret_cast<const int4*>(tgt + start);

    for (int v = tid; v < nv; v += SCAT_THREADS) {
        const float4 ev = e4[v];
        const int4 tv = t4[v];
        int t;
        t = tv.x - base; if ((unsigned)t < (unsigned)CHUNK2) atomicAdd(&hist[t], __expf(ev.x));
        t = tv.y - base; if ((unsigned)t < (unsigned)CHUNK2) atomicAdd(&hist[t], __expf(ev.y));
        t = tv.z - base; if ((unsigned)t < (unsigned)CHUNK2) atomicAdd(&hist[t], __expf(ev.z));
        t = tv.w - base; if ((unsigned)t < (unsigned)CHUNK2) atomicAdd(&hist[t], __expf(ev.w));
    }
    for (int i = tail_lo + tid; i < tail_hi; i += SCAT_THREADS) {
        const int t = tgt[start + i] - base;
        if ((unsigned)t < (unsigned)CHUNK2) atomicAdd(&hist[t], __expf(e[start + i]));
    }
    __syncthreads();

    // flush chunk histogram as packed bf16x2 (36 KB out)
    unsigned* dst = reinterpret_cast<unsigned*>(
        partials + ((size_t)slice * NCH + ch) * CHUNK2);
    const float2* h2 = reinterpret_cast<const float2*>(hist);
    for (int j = tid; j < (CHUNK2 / 2); j += SCAT_THREADS) {
        const float2 hv = h2[j];
        dst[j] = bf16rne(hv.x) | (bf16rne(hv.y) << 16);
    }
}

// ---- pass 2a: partial reduce (NSUB sub-groups of B_S/NSUB slice-copies) ----
__global__ void gat_reduce1(const unsigned short* __restrict__ partials,
                            float* __restrict__ subsums) {
    const int nq = CCAP >> 2;                    // 27648 float4-slots
    const int t = blockIdx.x * blockDim.x + threadIdx.x;
    if (t >= nq * NSUB) return;
    const int s = t / nq;                        // nq % 64 == 0: wave-uniform
    const int q = t - s * nq;
    const int nd = q * 4;
    const int bps = B_S / NSUB;                  // 16
    const int b0 = s * bps;

    const unsigned short* p = partials + nd;
    float s0 = 0.f, s1 = 0.f, s2 = 0.f, s3 = 0.f;
    float r0 = 0.f, r1 = 0.f, r2 = 0.f, r3 = 0.f;
    for (int b = b0; b + 1 < b0 + bps; b += 2) {
        const ushort4 va = *reinterpret_cast<const ushort4*>(p + (size_t)b * CCAP);
        const ushort4 vb = *reinterpret_cast<const ushort4*>(p + (size_t)(b + 1) * CCAP);
        s0 += bf16tof(va.x); s1 += bf16tof(va.y);
        s2 += bf16tof(va.z); s3 += bf16tof(va.w);
        r0 += bf16tof(vb.x); r1 += bf16tof(vb.y);
        r2 += bf16tof(vb.z); r3 += bf16tof(vb.w);
    }
    float4 o;
    o.x = s0 + r0; o.y = s1 + r1; o.z = s2 + r2; o.w = s3 + r3;
    *reinterpret_cast<float4*>(subsums + (size_t)s * CCAP + nd) = o;
}

// ---- pass 2b: combine subsums -> sums ----
__global__ void gat_reduce2(const float* __restrict__ subsums,
                            const int* __restrict__ np,
                            float* __restrict__ sums) {
    const int n = *np;
    const int q = blockIdx.x * blockDim.x + threadIdx.x;
    const int nd = q * 4;
    if (nd >= CCAP) return;
    float4 acc; acc.x = acc.y = acc.z = acc.w = 0.f;
#pragma unroll
    for (int s = 0; s < NSUB; ++s) {
        const float4 v = *reinterpret_cast<const float4*>(
            subsums + (size_t)s * CCAP + nd);
        acc.x += v.x; acc.y += v.y; acc.z += v.z; acc.w += v.w;
    }
    if (nd + 4 <= n) {
        *reinterpret_cast<float4*>(sums + nd) = acc;
    } else {
        if (nd     < n) sums[nd]     = acc.x;
        if (nd + 1 < n) sums[nd + 1] = acc.y;
        if (nd + 2 < n) sums[nd + 2] = acc.z;
        if (nd + 3 < n) sums[nd + 3] = acc.w;
    }
}

// ---- fallback path (tiny ws): zero + device-scope atomic scatter ----
__global__ void gat_zero_sums(float* __restrict__ sums,
                              const int* __restrict__ np) {
    const int n = *np;
    const int stride = gridDim.x * blockDim.x;
    for (int i = blockIdx.x * blockDim.x + threadIdx.x; i < n; i += stride)
        sums[i] = 0.0f;
}

__global__ void gat_exp_scatter(const float4* __restrict__ e4,
                                const int4* __restrict__ t4,
                                const float* __restrict__ e,
                                const int* __restrict__ tgt,
                                float* __restrict__ sums,
                                int n4, int E) {
    const int stride = gridDim.x * blockDim.x;
    const int tid = blockIdx.x * blockDim.x + threadIdx.x;
    for (int i = tid; i < n4; i += stride) {
        const float4 ev = e4[i];
        const int4 tv = t4[i];
        atomicAdd(&sums[tv.x], __expf(ev.x));
        atomicAdd(&sums[tv.y], __expf(ev.y));
        atomicAdd(&sums[tv.z], __expf(ev.z));
        atomicAdd(&sums[tv.w], __expf(ev.w));
    }
    const int tail_base = n4 * 4;
    if (tid < E - tail_base)
        atomicAdd(&sums[tgt[tail_base + tid]], __expf(e[tail_base + tid]));
}

// ---- pass 3: normalize ----
__global__ void gat_normalize(const float4* __restrict__ e4,
                              const int4* __restrict__ t4,
                              const float* __restrict__ e,
                              const int* __restrict__ tgt,
                              const float* __restrict__ sums,
                              float4* __restrict__ out4,
                              float* __restrict__ out,
                              int n4, int E) {
    const int stride = gridDim.x * blockDim.x;
    const int tid = blockIdx.x * blockDim.x + threadIdx.x;
    for (int i = tid; i < n4; i += stride) {
        const float4 ev = e4[i];
        const int4 tv = t4[i];
        float4 r;
        r.x = __expf(ev.x) * __builtin_amdgcn_rcpf(sums[tv.x] + 1e-16f);
        r.y = __expf(ev.y) * __builtin_amdgcn_rcpf(sums[tv.y] + 1e-16f);
        r.z = __expf(ev.z) * __builtin_amdgcn_rcpf(sums[tv.z] + 1e-16f);
        r.w = __expf(ev.w) * __builtin_amdgcn_rcpf(sums[tv.w] + 1e-16f);
        out4[i] = r;
    }
    const int tail_base = n4 * 4;
    if (tid < E - tail_base) {
        const int i = tail_base + tid;
        out[i] = __expf(e[i]) * __builtin_amdgcn_rcpf(sums[tgt[i]] + 1e-16f);
    }
}

extern "C" void kernel_launch(void* const* d_in, const int* in_sizes, int n_in,
                              void* d_out, int out_size, void* d_ws, size_t ws_size,
                              hipStream_t stream) {
    const float* e = (const float*)d_in[0];
    const int* edge_index = (const int*)d_in[1];   // [2, E] row-major
    const int* num_nodes_p = (const int*)d_in[2];  // device scalar

    const int E = in_sizes[0];
    const int* tgt = edge_index + E;               // row 1 = target nodes

    float* sums = (float*)d_ws;                    // CCAP floats
    float* alpha = (float*)d_out;
    const int n4e = E / 4;

    const int per = (((E + B_S - 1) / B_S) + 3) & ~3;   // 50000 at E=6.4M

    const size_t need = PART_OFF + (size_t)B_S * CCAP * sizeof(unsigned short);
    const bool use_priv = ws_size >= need;

    if (use_priv) {
        float* subsums = (float*)((char*)d_ws + SUBS_OFF);
        unsigned short* partials = (unsigned short*)((char*)d_ws + PART_OFF);

        gat_scatter_sc<<<B_S * NCH, SCAT_THREADS, 0, stream>>>(
            e, tgt, partials, per, E);

        const int r1_threads = (CCAP / 4) * NSUB;       // 221184
        gat_reduce1<<<(r1_threads + 255) / 256, 256, 0, stream>>>(
            partials, subsums);

        gat_reduce2<<<(CCAP / 4 + 255) / 256, 256, 0, stream>>>(
            subsums, num_nodes_p, sums);
    } else {
        gat_zero_sums<<<512, 256, 0, stream>>>(sums, num_nodes_p);
        int blocks = (n4e + 255) / 256;
        if (blocks > 2048) blocks = 2048;
        if (blocks < 1) blocks = 1;
        gat_exp_scatter<<<blocks, 256, 0, stream>>>(
            (const float4*)e, (const int4*)tgt, e, tgt, sums, n4e, E);
    }

    {
        int blocks = (n4e + 255) / 256;   // one float4 per thread
        if (blocks < 1) blocks = 1;
        gat_normalize<<<blocks, 256, 0, stream>>>(
            (const float4*)e, (const int4*)tgt, e, tgt, sums,
            (float4*)alpha, alpha, n4e, E);
    }
}